// Round 5
// baseline (386.976 us; speedup 1.0000x reference)
//
#include <hip/hip_runtime.h>
#include <hip/hip_bf16.h>
#include <cstdint>
#include <cstddef>

// Problem constants (fixed by the reference)
#define N_NODES   50000
#define N_EDGES   640000
#define ETOT      (N_EDGES + N_NODES)   // edges + self loops = 690000
#define IN_DIM    128
#define HID       64
#define HEADS     8
#define F1        (HEADS * HID)         // 512
#define OUT_DIM   2
#define N_GRAPHS  64
#define NEG_SLOPE 0.2f
#define CAP       64   // in-degree ~ Poisson(12.8)+1 self-loop; P(deg>63)~1e-24

typedef __attribute__((ext_vector_type(8))) short s8v;    // 8 x bf16 (4 VGPR)
typedef __attribute__((ext_vector_type(4))) float f32x4;  // MFMA accumulator

__device__ __forceinline__ float leakyf(float x) { return x > 0.f ? x : NEG_SLOPE * x; }
__device__ __forceinline__ float eluf(float x)   { return x > 0.f ? x : __expf(x) - 1.f; }

__device__ __forceinline__ float bf2f(ushort u) {
    union { uint32_t i; float f; } c; c.i = ((uint32_t)u) << 16; return c.f;
}
__device__ __forceinline__ ushort f2bf(float f) {
    union { float f; uint32_t i; } c; c.f = f;
    uint32_t r = c.i + 0x7FFFu + ((c.i >> 16) & 1u);   // round-to-nearest-even
    return (ushort)(r >> 16);
}

// ----------------------------------- fused prep: padded-CSR fill + casts
#define XW_ITEMS  (N_NODES * IN_DIM / 4)        // 1600000 float4-casts
#define W1_ITEMS  (F1 * IN_DIM)                 // 65536
#define W2_ITEMS  (HID * F1)                    // 32768
#define PREP_ITEMS (ETOT + XW_ITEMS + W1_ITEMS + W2_ITEMS)

__global__ __launch_bounds__(256) void prep_fill(const int* __restrict__ srcI,
                                                 const int* __restrict__ dstI,
                                                 int* __restrict__ counts,
                                                 int* __restrict__ csrp,
                                                 const float* __restrict__ x,
                                                 const float* __restrict__ W1,
                                                 const float* __restrict__ W2,
                                                 ushort* __restrict__ xb,
                                                 ushort* __restrict__ W1T,
                                                 ushort* __restrict__ W2T) {
    int i = blockIdx.x * 256 + threadIdx.x;
    if (i < ETOT) {
        int s, d;
        if (i < N_EDGES) { s = srcI[i]; d = dstI[i]; }
        else             { s = d = i - N_EDGES; }
        int slot = atomicAdd(&counts[d], 1);
        if (slot < CAP) csrp[d * CAP + slot] = s;
    } else if (i < ETOT + XW_ITEMS) {
        int idx = i - ETOT;
        float4 v = *reinterpret_cast<const float4*>(x + (size_t)idx * 4);
        ushort4 u;
        u.x = f2bf(v.x); u.y = f2bf(v.y); u.z = f2bf(v.z); u.w = f2bf(v.w);
        *reinterpret_cast<ushort4*>(xb + (size_t)idx * 4) = u;
    } else if (i < ETOT + XW_ITEMS + W1_ITEMS) {
        int idx = i - ETOT - XW_ITEMS;
        int n = idx >> 7, k = idx & 127;         // W1T[n][k] = W1[k][n]
        W1T[idx] = f2bf(W1[(size_t)k * F1 + n]);
    } else if (i < PREP_ITEMS) {
        int idx = i - ETOT - XW_ITEMS - W1_ITEMS;
        int n = idx >> 9, k = idx & 511;         // W2T[n][k] = W2[k][n]
        W2T[idx] = f2bf(W2[(size_t)k * HID + n]);
    }
}

// ---------------------------------------------------------------- bf16 GEMM
// C[M,N] = A[M,K] @ BT[N,K]^T, bf16 in/out, f32 acc.
// blockIdx.x = col block (head, fast-varying -> A-tile reuse is L2-hot),
// blockIdx.y = row block. 4 waves stacked on rows; BN=64 so for layer 1 each
// col block IS one head -> attention logits (as,ad) fused into epilogue.
template<int BM, int BN, int BK, int AH>
__global__ __launch_bounds__(256) void gemm_att(const ushort* __restrict__ A,
                                                const ushort* __restrict__ BT,
                                                ushort* __restrict__ C,
                                                int M, int N, int K,
                                                const float* __restrict__ att_s,
                                                const float* __restrict__ att_d,
                                                float* __restrict__ as_o,
                                                float* __restrict__ ad_o) {
    __shared__ ushort As[BM * BK];   // XOR-swizzled
    __shared__ ushort Bs[BN * BK];
    const int t    = threadIdx.x;
    const int row0 = blockIdx.y * BM;
    const int col0 = blockIdx.x * BN;
    const int lane = t & 63;
    const int wr   = t >> 6;                 // 0..3, wave row band
    constexpr int FR = BM / 64;              // fragments per wave row band

    f32x4 acc[FR][4];
    #pragma unroll
    for (int i = 0; i < FR; ++i)
        #pragma unroll
        for (int j = 0; j < 4; ++j)
            acc[i][j] = (f32x4){0.f, 0.f, 0.f, 0.f};

    constexpr int A_IT = BM * BK / 8 / 256;  // 16B chunks per thread
    constexpr int B_IT = BN * BK / 8 / 256;

    for (int k0 = 0; k0 < K; k0 += BK) {
        #pragma unroll
        for (int i = 0; i < A_IT; ++i) {
            int ch  = t + 256 * i;
            int r   = ch >> 3;               // BK*2/16 = 8 chunks per row
            int c16 = ch & 7;
            uint4 v = make_uint4(0u, 0u, 0u, 0u);
            int gr = row0 + r;
            if (gr < M)
                v = *reinterpret_cast<const uint4*>(A + (size_t)gr * K + k0 + c16 * 8);
            int off = (ch * 16) ^ ((r & 7) << 4);
            *reinterpret_cast<uint4*>(reinterpret_cast<char*>(As) + off) = v;
        }
        #pragma unroll
        for (int i = 0; i < B_IT; ++i) {
            int ch  = t + 256 * i;
            int r   = ch >> 3;
            int c16 = ch & 7;
            uint4 v = *reinterpret_cast<const uint4*>(BT + (size_t)(col0 + r) * K + k0 + c16 * 8);
            int off = (ch * 16) ^ ((r & 7) << 4);
            *reinterpret_cast<uint4*>(reinterpret_cast<char*>(Bs) + off) = v;
        }
        __syncthreads();
        #pragma unroll
        for (int kk = 0; kk < BK; kk += 32) {
            s8v af[FR], bf[4];
            #pragma unroll
            for (int fr = 0; fr < FR; ++fr) {
                int r   = wr * (FR * 16) + fr * 16 + (lane & 15);
                int off = (r * (BK * 2) + kk * 2 + (lane >> 4) * 16) ^ ((r & 7) << 4);
                af[fr] = *reinterpret_cast<const s8v*>(reinterpret_cast<const char*>(As) + off);
            }
            #pragma unroll
            for (int fc = 0; fc < 4; ++fc) {
                int r   = fc * 16 + (lane & 15);
                int off = (r * (BK * 2) + kk * 2 + (lane >> 4) * 16) ^ ((r & 7) << 4);
                bf[fc] = *reinterpret_cast<const s8v*>(reinterpret_cast<const char*>(Bs) + off);
            }
            #pragma unroll
            for (int fr = 0; fr < FR; ++fr)
                #pragma unroll
                for (int fc = 0; fc < 4; ++fc)
                    acc[fr][fc] = __builtin_amdgcn_mfma_f32_16x16x32_bf16(af[fr], bf[fc], acc[fr][fc], 0, 0, 0);
        }
        __syncthreads();
    }

    // att vectors for this head (col block), at this lane's 4 columns
    float avs[4], avd[4];
    const float* asp = att_s + blockIdx.x * BN;
    const float* adp = att_d + blockIdx.x * BN;
    #pragma unroll
    for (int fc = 0; fc < 4; ++fc) {
        avs[fc] = asp[fc * 16 + (lane & 15)];
        avd[fc] = adp[fc * 16 + (lane & 15)];
    }

    // epilogue: C/D layout col=lane&15, row=(lane>>4)*4+reg  [m89-verified]
    #pragma unroll
    for (int fr = 0; fr < FR; ++fr) {
        #pragma unroll
        for (int j = 0; j < 4; ++j) {
            int row = row0 + wr * (FR * 16) + fr * 16 + (lane >> 4) * 4 + j;
            if (row < M) {
                float sv = 0.f, dv = 0.f;
                #pragma unroll
                for (int fc = 0; fc < 4; ++fc) {
                    float c = acc[fr][fc][j];
                    C[(size_t)row * N + col0 + fc * 16 + (lane & 15)] = f2bf(c);
                    sv = fmaf(c, avs[fc], sv);
                    dv = fmaf(c, avd[fc], dv);
                }
                #pragma unroll
                for (int off = 1; off < 16; off <<= 1) {
                    sv += __shfl_xor(sv, off);
                    dv += __shfl_xor(dv, off);
                }
                if ((lane & 15) == 0) {
                    as_o[(size_t)row * AH + blockIdx.x] = sv;
                    ad_o[(size_t)row * AH + blockIdx.x] = dv;
                }
            }
        }
    }
}

// ------------------------------------------- layer-1 aggregation (8 heads)
// one wave per dst; 4-edge software pipeline (named regs -> ~8 loads in
// flight per wave; round-4 VGPR=20 showed the compiler couldn't pipeline).
__global__ __launch_bounds__(256) void gat_agg1(const ushort* __restrict__ h,
                                                const float* __restrict__ as,
                                                const float* __restrict__ ad,
                                                const int* __restrict__ counts,
                                                const int* __restrict__ csrp,
                                                const float* __restrict__ bias,
                                                ushort* __restrict__ z) {
    int dst  = (blockIdx.x * 256 + threadIdx.x) >> 6;
    int lane = threadIdx.x & 63;
    if (dst >= N_NODES) return;
    int cnt = min(counts[dst], CAP);
    int hd  = lane >> 3;
    float adv = ad[(size_t)dst * HEADS + hd];
    int myidx = csrp[(size_t)dst * CAP + lane];   // lane j holds edge j's src

    float accv[8] = {0.f, 0.f, 0.f, 0.f, 0.f, 0.f, 0.f, 0.f};
    float den = 0.f;

    for (int j0 = 0; j0 < cnt; j0 += 4) {
        int n = cnt - j0;                         // wave-uniform
        int s0 = 0, s1 = 0, s2 = 0, s3 = 0;
        float a0 = 0.f, a1 = 0.f, a2 = 0.f, a3 = 0.f;
        s8v v0 = {}, v1 = {}, v2 = {}, v3 = {};
        // issue phase: independent gathers for up to 4 edges
        s0 = __shfl(myidx, j0);
        a0 = as[(size_t)s0 * HEADS + hd];
        v0 = *reinterpret_cast<const s8v*>(h + (size_t)s0 * F1 + lane * 8);
        if (n > 1) {
            s1 = __shfl(myidx, j0 + 1);
            a1 = as[(size_t)s1 * HEADS + hd];
            v1 = *reinterpret_cast<const s8v*>(h + (size_t)s1 * F1 + lane * 8);
        }
        if (n > 2) {
            s2 = __shfl(myidx, j0 + 2);
            a2 = as[(size_t)s2 * HEADS + hd];
            v2 = *reinterpret_cast<const s8v*>(h + (size_t)s2 * F1 + lane * 8);
        }
        if (n > 3) {
            s3 = __shfl(myidx, j0 + 3);
            a3 = as[(size_t)s3 * HEADS + hd];
            v3 = *reinterpret_cast<const s8v*>(h + (size_t)s3 * F1 + lane * 8);
        }
        // consume phase
        {
            float w = __expf(leakyf(a0 + adv));
            den += w;
            #pragma unroll
            for (int c = 0; c < 8; ++c) accv[c] = fmaf(w, bf2f((ushort)v0[c]), accv[c]);
        }
        if (n > 1) {
            float w = __expf(leakyf(a1 + adv));
            den += w;
            #pragma unroll
            for (int c = 0; c < 8; ++c) accv[c] = fmaf(w, bf2f((ushort)v1[c]), accv[c]);
        }
        if (n > 2) {
            float w = __expf(leakyf(a2 + adv));
            den += w;
            #pragma unroll
            for (int c = 0; c < 8; ++c) accv[c] = fmaf(w, bf2f((ushort)v2[c]), accv[c]);
        }
        if (n > 3) {
            float w = __expf(leakyf(a3 + adv));
            den += w;
            #pragma unroll
            for (int c = 0; c < 8; ++c) accv[c] = fmaf(w, bf2f((ushort)v3[c]), accv[c]);
        }
    }
    float inv = 1.f / (den + 1e-16f);
    s8v ov;
    #pragma unroll
    for (int c = 0; c < 8; ++c) {
        float v = accv[c] * inv + bias[lane * 8 + c];
        ov[c] = (short)f2bf(eluf(v));
    }
    *reinterpret_cast<s8v*>(z + (size_t)dst * F1 + lane * 8) = ov;
}

// ------------------------------------------- layer-2 aggregation (1 head)
__global__ __launch_bounds__(256) void gat_agg2(const ushort* __restrict__ h,
                                                const float* __restrict__ as,
                                                const float* __restrict__ ad,
                                                const int* __restrict__ counts,
                                                const int* __restrict__ csrp,
                                                const float* __restrict__ bias,
                                                float* __restrict__ z) {
    int dst  = (blockIdx.x * 256 + threadIdx.x) >> 6;
    int lane = threadIdx.x & 63;
    if (dst >= N_NODES) return;
    int cnt = min(counts[dst], CAP);
    float adv = ad[dst];
    int myidx = csrp[(size_t)dst * CAP + lane];

    float acc = 0.f, den = 0.f;
    for (int j0 = 0; j0 < cnt; j0 += 4) {
        int n = cnt - j0;
        int s0 = 0, s1 = 0, s2 = 0, s3 = 0;
        float a0 = 0.f, a1 = 0.f, a2 = 0.f, a3 = 0.f;
        ushort u0 = 0, u1 = 0, u2 = 0, u3 = 0;
        s0 = __shfl(myidx, j0);
        a0 = as[s0]; u0 = h[(size_t)s0 * HID + lane];
        if (n > 1) { s1 = __shfl(myidx, j0 + 1); a1 = as[s1]; u1 = h[(size_t)s1 * HID + lane]; }
        if (n > 2) { s2 = __shfl(myidx, j0 + 2); a2 = as[s2]; u2 = h[(size_t)s2 * HID + lane]; }
        if (n > 3) { s3 = __shfl(myidx, j0 + 3); a3 = as[s3]; u3 = h[(size_t)s3 * HID + lane]; }
        {
            float w = __expf(leakyf(a0 + adv));
            den += w; acc = fmaf(w, bf2f(u0), acc);
        }
        if (n > 1) { float w = __expf(leakyf(a1 + adv)); den += w; acc = fmaf(w, bf2f(u1), acc); }
        if (n > 2) { float w = __expf(leakyf(a2 + adv)); den += w; acc = fmaf(w, bf2f(u2), acc); }
        if (n > 3) { float w = __expf(leakyf(a3 + adv)); den += w; acc = fmaf(w, bf2f(u3), acc); }
    }
    float v = acc / (den + 1e-16f) + bias[lane];
    z[(size_t)dst * HID + lane] = eluf(v);
}

// --------------------------------------- fused mean-pool + FC (per graph)
// one block per graph; batch is sorted -> binary search the node range.
__global__ __launch_bounds__(256) void pool_fc(const float* __restrict__ z,
                                               const int* __restrict__ batch,
                                               const float* __restrict__ fc_w,
                                               const float* __restrict__ fc_b,
                                               float* __restrict__ out) {
    int g = blockIdx.x;
    int t = threadIdx.x, lane = t & 63, w = t >> 6;
    auto lb = [&](int key) {
        int lo = 0, hi = N_NODES;
        while (lo < hi) { int mid = (lo + hi) >> 1; if (batch[mid] < key) lo = mid + 1; else hi = mid; }
        return lo;
    };
    int lo = lb(g), hi = lb(g + 1);
    float acc = 0.f;
    for (int n = lo + w; n < hi; n += 4)
        acc += z[(size_t)n * HID + lane];
    __shared__ float sh[4][HID];
    sh[w][lane] = acc;
    __syncthreads();
    if (w == 0) {
        float s = sh[0][lane] + sh[1][lane] + sh[2][lane] + sh[3][lane];
        float cntf = fmaxf((float)(hi - lo), 1.f);
        float mean = s / cntf;
        float p0 = mean * fc_w[lane * OUT_DIM + 0];
        float p1 = mean * fc_w[lane * OUT_DIM + 1];
        #pragma unroll
        for (int off = 32; off > 0; off >>= 1) {
            p0 += __shfl_xor(p0, off);
            p1 += __shfl_xor(p1, off);
        }
        if (lane == 0) {
            out[g * OUT_DIM + 0] = p0 + fc_b[0];
            out[g * OUT_DIM + 1] = p1 + fc_b[1];
        }
    }
}

// ---------------------------------------------------------------- launcher
extern "C" void kernel_launch(void* const* d_in, const int* in_sizes, int n_in,
                              void* d_out, int out_size, void* d_ws, size_t ws_size,
                              hipStream_t stream) {
    const float* x    = (const float*)d_in[0];
    const float* W1   = (const float*)d_in[1];
    const float* at_s1= (const float*)d_in[2];
    const float* at_d1= (const float*)d_in[3];
    const float* b1   = (const float*)d_in[4];
    const float* W2   = (const float*)d_in[5];
    const float* at_s2= (const float*)d_in[6];
    const float* at_d2= (const float*)d_in[7];
    const float* b2   = (const float*)d_in[8];
    const float* fcw  = (const float*)d_in[9];
    const float* fcb  = (const float*)d_in[10];
    const int*   ei   = (const int*)d_in[11];
    const int*   batch= (const int*)d_in[12];
    float* out = (float*)d_out;

    char* p = (char*)d_ws;
    auto alloc = [&](size_t bytes) {
        char* r = p;
        p += (bytes + 255) & ~size_t(255);
        return r;
    };
    int*    counts= (int*)alloc((size_t)N_NODES * 4);
    ushort* xb    = (ushort*)alloc((size_t)N_NODES * IN_DIM * 2);
    ushort* W1T   = (ushort*)alloc((size_t)F1 * IN_DIM * 2);
    ushort* W2T   = (ushort*)alloc((size_t)HID * F1 * 2);
    ushort* h1    = (ushort*)alloc((size_t)N_NODES * F1 * 2);
    ushort* z1    = (ushort*)alloc((size_t)N_NODES * F1 * 2);
    ushort* h2    = (ushort*)alloc((size_t)N_NODES * HID * 2);
    float*  z2    = (float*)alloc((size_t)N_NODES * HID * 4);
    float*  as1   = (float*)alloc((size_t)N_NODES * HEADS * 4);
    float*  ad1   = (float*)alloc((size_t)N_NODES * HEADS * 4);
    float*  as2   = (float*)alloc((size_t)N_NODES * 4);
    float*  ad2   = (float*)alloc((size_t)N_NODES * 4);
    int*    csrp  = (int*)alloc((size_t)N_NODES * CAP * 4);

    const int* srcI = ei;
    const int* dstI = ei + N_EDGES;

    hipMemsetAsync(counts, 0, (size_t)N_NODES * 4, stream);

    // fused: padded-CSR fill + bf16 casts/transposes (1 kernel)
    prep_fill<<<(PREP_ITEMS + 255) / 256, 256, 0, stream>>>(
        srcI, dstI, counts, csrp, x, W1, W2, xb, W1T, W2T);

    // Layer 1: h1 = xb @ W1 with fused as1/ad1 epilogue (blockIdx.x = head)
    dim3 g1(F1 / 64, (N_NODES + 127) / 128);
    gemm_att<128, 64, 64, HEADS><<<g1, 256, 0, stream>>>(
        xb, W1T, h1, N_NODES, F1, IN_DIM, at_s1, at_d1, as1, ad1);
    gat_agg1<<<(N_NODES + 3) / 4, 256, 0, stream>>>(h1, as1, ad1, counts, csrp, b1, z1);

    // Layer 2: h2 = z1 @ W2 with fused as2/ad2 epilogue
    dim3 g2(1, (N_NODES + 63) / 64);
    gemm_att<64, 64, 64, 1><<<g2, 256, 0, stream>>>(
        z1, W2T, h2, N_NODES, HID, F1, at_s2, at_d2, as2, ad2);
    gat_agg2<<<(N_NODES + 3) / 4, 256, 0, stream>>>(h2, as2, ad2, counts, csrp, b2, z2);

    // fused mean-pool + FC (one block per graph)
    pool_fc<<<N_GRAPHS, 256, 0, stream>>>(z2, batch, fcw, fcb, out);
}

// Round 7
// 328.672 us; speedup vs baseline: 1.1774x; 1.1774x over previous
//
#include <hip/hip_runtime.h>
#include <hip/hip_bf16.h>
#include <cstdint>
#include <cstddef>

// Problem constants (fixed by the reference)
#define N_NODES   50000
#define N_EDGES   640000
#define ETOT      (N_EDGES + N_NODES)   // edges + self loops = 690000
#define IN_DIM    128
#define HID       64
#define HEADS     8
#define F1        (HEADS * HID)         // 512
#define OUT_DIM   2
#define N_GRAPHS  64
#define NEG_SLOPE 0.2f
#define CAP       64   // in-degree ~ Poisson(12.8)+1 self-loop; P(deg>63)~1e-24

typedef __attribute__((ext_vector_type(8))) short s8v;    // 8 x bf16 (4 VGPR)
typedef __attribute__((ext_vector_type(4))) float f32x4;  // MFMA accumulator
typedef unsigned char uchar;
typedef unsigned int  uint;

__device__ __forceinline__ float leakyf(float x) { return x > 0.f ? x : NEG_SLOPE * x; }
__device__ __forceinline__ float eluf(float x)   { return x > 0.f ? x : __expf(x) - 1.f; }

__device__ __forceinline__ float bf2f(ushort u) {
    union { uint32_t i; float f; } c; c.i = ((uint32_t)u) << 16; return c.f;
}
__device__ __forceinline__ ushort f2bf(float f) {
    union { float f; uint32_t i; } c; c.f = f;
    uint32_t r = c.i + 0x7FFFu + ((c.i >> 16) & 1u);   // round-to-nearest-even
    return (ushort)(r >> 16);
}
// HW fp8 e4m3 (OCP on gfx950) converts; sel must be an immediate -> template
template<int SEL>
__device__ __forceinline__ float fp8f(uint w) {
    return __builtin_amdgcn_cvt_f32_fp8(w, SEL);
}
__device__ __forceinline__ uchar f2fp8(float f) {
    uint p = __builtin_amdgcn_cvt_pk_fp8_f32(f, f, 0u, false);
    return (uchar)(p & 0xFFu);
}

// ----------------------------------- fused prep: padded-CSR fill + casts
#define XW_ITEMS  (N_NODES * IN_DIM / 4)        // 1600000 float4-casts
#define W1_ITEMS  (F1 * IN_DIM)                 // 65536
#define W2_ITEMS  (HID * F1)                    // 32768
#define PREP_ITEMS (ETOT + XW_ITEMS + W1_ITEMS + W2_ITEMS)

__global__ __launch_bounds__(256) void prep_fill(const int* __restrict__ srcI,
                                                 const int* __restrict__ dstI,
                                                 int* __restrict__ counts,
                                                 int* __restrict__ csrp,
                                                 const float* __restrict__ x,
                                                 const float* __restrict__ W1,
                                                 const float* __restrict__ W2,
                                                 ushort* __restrict__ xb,
                                                 ushort* __restrict__ W1T,
                                                 ushort* __restrict__ W2T) {
    int i = blockIdx.x * 256 + threadIdx.x;
    if (i < ETOT) {
        int s, d;
        if (i < N_EDGES) { s = srcI[i]; d = dstI[i]; }
        else             { s = d = i - N_EDGES; }
        int slot = atomicAdd(&counts[d], 1);
        if (slot < CAP) csrp[d * CAP + slot] = s;
    } else if (i < ETOT + XW_ITEMS) {
        int idx = i - ETOT;
        float4 v = *reinterpret_cast<const float4*>(x + (size_t)idx * 4);
        ushort4 u;
        u.x = f2bf(v.x); u.y = f2bf(v.y); u.z = f2bf(v.z); u.w = f2bf(v.w);
        *reinterpret_cast<ushort4*>(xb + (size_t)idx * 4) = u;
    } else if (i < ETOT + XW_ITEMS + W1_ITEMS) {
        int idx = i - ETOT - XW_ITEMS;
        int n = idx >> 7, k = idx & 127;         // W1T[n][k] = W1[k][n]
        W1T[idx] = f2bf(W1[(size_t)k * F1 + n]);
    } else if (i < PREP_ITEMS) {
        int idx = i - ETOT - XW_ITEMS - W1_ITEMS;
        int n = idx >> 9, k = idx & 511;         // W2T[n][k] = W2[k][n]
        W2T[idx] = f2bf(W2[(size_t)k * HID + n]);
    }
}

// ---------------------------------------------------------------- bf16 GEMM
// C[M,N] = A[M,K] @ BT[N,K]^T, bf16 in, f32 acc, **fp8 e4m3 out** (C feeds
// only the aggregation gathers). Attention logits as/ad come from the exact
// f32 accumulators in the epilogue (BN=64 -> col block == head for layer 1).
template<int BM, int BN, int BK, int AH>
__global__ __launch_bounds__(256) void gemm_att(const ushort* __restrict__ A,
                                                const ushort* __restrict__ BT,
                                                uchar* __restrict__ C8,
                                                int M, int N, int K,
                                                const float* __restrict__ att_s,
                                                const float* __restrict__ att_d,
                                                float* __restrict__ as_o,
                                                float* __restrict__ ad_o,
                                                ushort* __restrict__ Cb) {
    __shared__ ushort As[BM * BK];   // XOR-swizzled
    __shared__ ushort Bs[BN * BK];
    const int t    = threadIdx.x;
    const int row0 = blockIdx.y * BM;
    const int col0 = blockIdx.x * BN;
    const int lane = t & 63;
    const int wr   = t >> 6;                 // 0..3, wave row band
    constexpr int FR = BM / 64;              // fragments per wave row band

    f32x4 acc[FR][4];
    #pragma unroll
    for (int i = 0; i < FR; ++i)
        #pragma unroll
        for (int j = 0; j < 4; ++j)
            acc[i][j] = (f32x4){0.f, 0.f, 0.f, 0.f};

    constexpr int A_IT = BM * BK / 8 / 256;  // 16B chunks per thread
    constexpr int B_IT = BN * BK / 8 / 256;

    for (int k0 = 0; k0 < K; k0 += BK) {
        #pragma unroll
        for (int i = 0; i < A_IT; ++i) {
            int ch  = t + 256 * i;
            int r   = ch >> 3;               // BK*2/16 = 8 chunks per row
            int c16 = ch & 7;
            uint4 v = make_uint4(0u, 0u, 0u, 0u);
            int gr = row0 + r;
            if (gr < M)
                v = *reinterpret_cast<const uint4*>(A + (size_t)gr * K + k0 + c16 * 8);
            int off = (ch * 16) ^ ((r & 7) << 4);
            *reinterpret_cast<uint4*>(reinterpret_cast<char*>(As) + off) = v;
        }
        #pragma unroll
        for (int i = 0; i < B_IT; ++i) {
            int ch  = t + 256 * i;
            int r   = ch >> 3;
            int c16 = ch & 7;
            uint4 v = *reinterpret_cast<const uint4*>(BT + (size_t)(col0 + r) * K + k0 + c16 * 8);
            int off = (ch * 16) ^ ((r & 7) << 4);
            *reinterpret_cast<uint4*>(reinterpret_cast<char*>(Bs) + off) = v;
        }
        __syncthreads();
        #pragma unroll
        for (int kk = 0; kk < BK; kk += 32) {
            s8v af[FR], bf[4];
            #pragma unroll
            for (int fr = 0; fr < FR; ++fr) {
                int r   = wr * (FR * 16) + fr * 16 + (lane & 15);
                int off = (r * (BK * 2) + kk * 2 + (lane >> 4) * 16) ^ ((r & 7) << 4);
                af[fr] = *reinterpret_cast<const s8v*>(reinterpret_cast<const char*>(As) + off);
            }
            #pragma unroll
            for (int fc = 0; fc < 4; ++fc) {
                int r   = fc * 16 + (lane & 15);
                int off = (r * (BK * 2) + kk * 2 + (lane >> 4) * 16) ^ ((r & 7) << 4);
                bf[fc] = *reinterpret_cast<const s8v*>(reinterpret_cast<const char*>(Bs) + off);
            }
            #pragma unroll
            for (int fr = 0; fr < FR; ++fr)
                #pragma unroll
                for (int fc = 0; fc < 4; ++fc)
                    acc[fr][fc] = __builtin_amdgcn_mfma_f32_16x16x32_bf16(af[fr], bf[fc], acc[fr][fc], 0, 0, 0);
        }
        __syncthreads();
    }

    // att vectors for this head (col block), at this lane's 4 columns
    float avs[4], avd[4];
    const float* asp = att_s + blockIdx.x * BN;
    const float* adp = att_d + blockIdx.x * BN;
    #pragma unroll
    for (int fc = 0; fc < 4; ++fc) {
        avs[fc] = asp[fc * 16 + (lane & 15)];
        avd[fc] = adp[fc * 16 + (lane & 15)];
    }

    // epilogue: C/D layout col=lane&15, row=(lane>>4)*4+reg  [m89-verified]
    #pragma unroll
    for (int fr = 0; fr < FR; ++fr) {
        #pragma unroll
        for (int j = 0; j < 4; ++j) {
            int row = row0 + wr * (FR * 16) + fr * 16 + (lane >> 4) * 4 + j;
            if (row < M) {
                float sv = 0.f, dv = 0.f;
                #pragma unroll
                for (int fc = 0; fc < 4; ++fc) {
                    float c = acc[fr][fc][j];
                    int col = col0 + fc * 16 + (lane & 15);
                    C8[(size_t)row * N + col] = f2fp8(c);
                    if (Cb) Cb[(size_t)row * N + col] = f2bf(c);
                    sv = fmaf(c, avs[fc], sv);
                    dv = fmaf(c, avd[fc], dv);
                }
                #pragma unroll
                for (int off = 1; off < 16; off <<= 1) {
                    sv += __shfl_xor(sv, off);
                    dv += __shfl_xor(dv, off);
                }
                if ((lane & 15) == 0) {
                    as_o[(size_t)row * AH + blockIdx.x] = sv;
                    ad_o[(size_t)row * AH + blockIdx.x] = dv;
                }
            }
        }
    }
}

// ------------------------------------------- layer-1 aggregation (8 heads)
// phase 1: lane = edge -> ONE exp instruction covers 64 edges per head
//          (weights stored in padded LDS [8][65], bank-conflict-free).
// phase 2: lane = channel-group; 4-deep pipelined fp8 gathers (8B/lane).
__global__ __launch_bounds__(256) void gat_agg1(const uchar* __restrict__ h8,
                                                const float* __restrict__ as,
                                                const float* __restrict__ ad,
                                                const int* __restrict__ counts,
                                                const int* __restrict__ csrp,
                                                const float* __restrict__ bias,
                                                ushort* __restrict__ z) {
    __shared__ float lds_w[4][HEADS][CAP + 1];
    int tid  = threadIdx.x;
    int wid  = tid >> 6;
    int dst  = (blockIdx.x * 256 + tid) >> 6;
    int lane = tid & 63;
    if (dst >= N_NODES) return;
    int cnt = min(counts[dst], CAP);
    int hd  = lane >> 3;

    // ---- phase 1: per-edge all-head weights
    int myidx = (lane < cnt) ? csrp[(size_t)dst * CAP + lane] : 0;
    float4 a0 = *reinterpret_cast<const float4*>(as + (size_t)myidx * HEADS);
    float4 a1 = *reinterpret_cast<const float4*>(as + (size_t)myidx * HEADS + 4);
    float4 d0 = *reinterpret_cast<const float4*>(ad + (size_t)dst * HEADS);
    float4 d1 = *reinterpret_cast<const float4*>(ad + (size_t)dst * HEADS + 4);
    lds_w[wid][0][lane] = __expf(leakyf(a0.x + d0.x));
    lds_w[wid][1][lane] = __expf(leakyf(a0.y + d0.y));
    lds_w[wid][2][lane] = __expf(leakyf(a0.z + d0.z));
    lds_w[wid][3][lane] = __expf(leakyf(a0.w + d0.w));
    lds_w[wid][4][lane] = __expf(leakyf(a1.x + d1.x));
    lds_w[wid][5][lane] = __expf(leakyf(a1.y + d1.y));
    lds_w[wid][6][lane] = __expf(leakyf(a1.z + d1.z));
    lds_w[wid][7][lane] = __expf(leakyf(a1.w + d1.w));
    // same wave produces & consumes -> no barrier needed (lgkmcnt ordering)

    // ---- phase 2: weighted fp8 gather-accumulate
    float accv[8] = {0.f, 0.f, 0.f, 0.f, 0.f, 0.f, 0.f, 0.f};
    float den = 0.f;
    const uchar* hb = h8 + (size_t)lane * 8;     // this lane's 8 channels
    for (int j0 = 0; j0 < cnt; j0 += 4) {
        int n = cnt - j0;                         // wave-uniform
        int s0 = 0, s1 = 0, s2 = 0, s3 = 0;
        uint2 v0 = {}, v1 = {}, v2 = {}, v3 = {};
        float w0 = 0.f, w1 = 0.f, w2 = 0.f, w3 = 0.f;
        s0 = __shfl(myidx, j0);
        v0 = *reinterpret_cast<const uint2*>(hb + (size_t)s0 * F1);
        w0 = lds_w[wid][hd][j0];
        if (n > 1) {
            s1 = __shfl(myidx, j0 + 1);
            v1 = *reinterpret_cast<const uint2*>(hb + (size_t)s1 * F1);
            w1 = lds_w[wid][hd][j0 + 1];
        }
        if (n > 2) {
            s2 = __shfl(myidx, j0 + 2);
            v2 = *reinterpret_cast<const uint2*>(hb + (size_t)s2 * F1);
            w2 = lds_w[wid][hd][j0 + 2];
        }
        if (n > 3) {
            s3 = __shfl(myidx, j0 + 3);
            v3 = *reinterpret_cast<const uint2*>(hb + (size_t)s3 * F1);
            w3 = lds_w[wid][hd][j0 + 3];
        }
        {
            den += w0;
            accv[0] = fmaf(w0, fp8f<0>(v0.x), accv[0]);
            accv[1] = fmaf(w0, fp8f<1>(v0.x), accv[1]);
            accv[2] = fmaf(w0, fp8f<2>(v0.x), accv[2]);
            accv[3] = fmaf(w0, fp8f<3>(v0.x), accv[3]);
            accv[4] = fmaf(w0, fp8f<0>(v0.y), accv[4]);
            accv[5] = fmaf(w0, fp8f<1>(v0.y), accv[5]);
            accv[6] = fmaf(w0, fp8f<2>(v0.y), accv[6]);
            accv[7] = fmaf(w0, fp8f<3>(v0.y), accv[7]);
        }
        if (n > 1) {
            den += w1;
            accv[0] = fmaf(w1, fp8f<0>(v1.x), accv[0]);
            accv[1] = fmaf(w1, fp8f<1>(v1.x), accv[1]);
            accv[2] = fmaf(w1, fp8f<2>(v1.x), accv[2]);
            accv[3] = fmaf(w1, fp8f<3>(v1.x), accv[3]);
            accv[4] = fmaf(w1, fp8f<0>(v1.y), accv[4]);
            accv[5] = fmaf(w1, fp8f<1>(v1.y), accv[5]);
            accv[6] = fmaf(w1, fp8f<2>(v1.y), accv[6]);
            accv[7] = fmaf(w1, fp8f<3>(v1.y), accv[7]);
        }
        if (n > 2) {
            den += w2;
            accv[0] = fmaf(w2, fp8f<0>(v2.x), accv[0]);
            accv[1] = fmaf(w2, fp8f<1>(v2.x), accv[1]);
            accv[2] = fmaf(w2, fp8f<2>(v2.x), accv[2]);
            accv[3] = fmaf(w2, fp8f<3>(v2.x), accv[3]);
            accv[4] = fmaf(w2, fp8f<0>(v2.y), accv[4]);
            accv[5] = fmaf(w2, fp8f<1>(v2.y), accv[5]);
            accv[6] = fmaf(w2, fp8f<2>(v2.y), accv[6]);
            accv[7] = fmaf(w2, fp8f<3>(v2.y), accv[7]);
        }
        if (n > 3) {
            den += w3;
            accv[0] = fmaf(w3, fp8f<0>(v3.x), accv[0]);
            accv[1] = fmaf(w3, fp8f<1>(v3.x), accv[1]);
            accv[2] = fmaf(w3, fp8f<2>(v3.x), accv[2]);
            accv[3] = fmaf(w3, fp8f<3>(v3.x), accv[3]);
            accv[4] = fmaf(w3, fp8f<0>(v3.y), accv[4]);
            accv[5] = fmaf(w3, fp8f<1>(v3.y), accv[5]);
            accv[6] = fmaf(w3, fp8f<2>(v3.y), accv[6]);
            accv[7] = fmaf(w3, fp8f<3>(v3.y), accv[7]);
        }
    }
    float inv = 1.f / (den + 1e-16f);
    s8v ov;
    #pragma unroll
    for (int c = 0; c < 8; ++c) {
        float v = accv[c] * inv + bias[lane * 8 + c];
        ov[c] = (short)f2bf(eluf(v));
    }
    *reinterpret_cast<s8v*>(z + (size_t)dst * F1 + lane * 8) = ov;
}

// ------------------------------------------- layer-2 aggregation (1 head)
// phase 1: lane = edge, weights in registers; phase 2: 1B/lane fp8 gather.
__global__ __launch_bounds__(256) void gat_agg2(const uchar* __restrict__ h8,
                                                const float* __restrict__ as,
                                                const float* __restrict__ ad,
                                                const int* __restrict__ counts,
                                                const int* __restrict__ csrp,
                                                const float* __restrict__ bias,
                                                float* __restrict__ z) {
    int dst  = (blockIdx.x * 256 + threadIdx.x) >> 6;
    int lane = threadIdx.x & 63;
    if (dst >= N_NODES) return;
    int cnt = min(counts[dst], CAP);
    float adv = ad[dst];

    int myidx = (lane < cnt) ? csrp[(size_t)dst * CAP + lane] : 0;
    float wl  = (lane < cnt) ? __expf(leakyf(as[myidx] + adv)) : 0.f;
    float den = wl;
    #pragma unroll
    for (int off = 32; off > 0; off >>= 1) den += __shfl_xor(den, off);

    float acc = 0.f;
    for (int j0 = 0; j0 < cnt; j0 += 4) {
        int n = cnt - j0;
        int s0 = 0, s1 = 0, s2 = 0, s3 = 0;
        float w0 = 0.f, w1 = 0.f, w2 = 0.f, w3 = 0.f;
        uint b0 = 0, b1 = 0, b2 = 0, b3 = 0;
        s0 = __shfl(myidx, j0);     w0 = __shfl(wl, j0);
        b0 = h8[(size_t)s0 * HID + lane];
        if (n > 1) { s1 = __shfl(myidx, j0 + 1); w1 = __shfl(wl, j0 + 1); b1 = h8[(size_t)s1 * HID + lane]; }
        if (n > 2) { s2 = __shfl(myidx, j0 + 2); w2 = __shfl(wl, j0 + 2); b2 = h8[(size_t)s2 * HID + lane]; }
        if (n > 3) { s3 = __shfl(myidx, j0 + 3); w3 = __shfl(wl, j0 + 3); b3 = h8[(size_t)s3 * HID + lane]; }
        acc = fmaf(w0, fp8f<0>(b0), acc);
        if (n > 1) acc = fmaf(w1, fp8f<0>(b1), acc);
        if (n > 2) acc = fmaf(w2, fp8f<0>(b2), acc);
        if (n > 3) acc = fmaf(w3, fp8f<0>(b3), acc);
    }
    float v = acc / (den + 1e-16f) + bias[lane];
    z[(size_t)dst * HID + lane] = eluf(v);
}

// --------------------------------------- fused mean-pool + FC (per graph)
__global__ __launch_bounds__(256) void pool_fc(const float* __restrict__ z,
                                               const int* __restrict__ batch,
                                               const float* __restrict__ fc_w,
                                               const float* __restrict__ fc_b,
                                               float* __restrict__ out) {
    int g = blockIdx.x;
    int t = threadIdx.x, lane = t & 63, w = t >> 6;
    auto lb = [&](int key) {
        int lo = 0, hi = N_NODES;
        while (lo < hi) { int mid = (lo + hi) >> 1; if (batch[mid] < key) lo = mid + 1; else hi = mid; }
        return lo;
    };
    int lo = lb(g), hi = lb(g + 1);
    float acc = 0.f;
    for (int n = lo + w; n < hi; n += 4)
        acc += z[(size_t)n * HID + lane];
    __shared__ float sh[4][HID];
    sh[w][lane] = acc;
    __syncthreads();
    if (w == 0) {
        float s = sh[0][lane] + sh[1][lane] + sh[2][lane] + sh[3][lane];
        float cntf = fmaxf((float)(hi - lo), 1.f);
        float mean = s / cntf;
        float p0 = mean * fc_w[lane * OUT_DIM + 0];
        float p1 = mean * fc_w[lane * OUT_DIM + 1];
        #pragma unroll
        for (int off = 32; off > 0; off >>= 1) {
            p0 += __shfl_xor(p0, off);
            p1 += __shfl_xor(p1, off);
        }
        if (lane == 0) {
            out[g * OUT_DIM + 0] = p0 + fc_b[0];
            out[g * OUT_DIM + 1] = p1 + fc_b[1];
        }
    }
}

// ---------------------------------------------------------------- launcher
extern "C" void kernel_launch(void* const* d_in, const int* in_sizes, int n_in,
                              void* d_out, int out_size, void* d_ws, size_t ws_size,
                              hipStream_t stream) {
    const float* x    = (const float*)d_in[0];
    const float* W1   = (const float*)d_in[1];
    const float* at_s1= (const float*)d_in[2];
    const float* at_d1= (const float*)d_in[3];
    const float* b1   = (const float*)d_in[4];
    const float* W2   = (const float*)d_in[5];
    const float* at_s2= (const float*)d_in[6];
    const float* at_d2= (const float*)d_in[7];
    const float* b2   = (const float*)d_in[8];
    const float* fcw  = (const float*)d_in[9];
    const float* fcb  = (const float*)d_in[10];
    const int*   ei   = (const int*)d_in[11];
    const int*   batch= (const int*)d_in[12];
    float* out = (float*)d_out;

    char* p = (char*)d_ws;
    auto alloc = [&](size_t bytes) {
        char* r = p;
        p += (bytes + 255) & ~size_t(255);
        return r;
    };
    int*    counts= (int*)alloc((size_t)N_NODES * 4);
    ushort* xb    = (ushort*)alloc((size_t)N_NODES * IN_DIM * 2);
    ushort* W1T   = (ushort*)alloc((size_t)F1 * IN_DIM * 2);
    ushort* W2T   = (ushort*)alloc((size_t)HID * F1 * 2);
    uchar*  h1    = (uchar*)alloc((size_t)N_NODES * F1);       // fp8 e4m3
    ushort* z1    = (ushort*)alloc((size_t)N_NODES * F1 * 2);  // bf16
    uchar*  h2    = (uchar*)alloc((size_t)N_NODES * HID);      // fp8 e4m3
    float*  z2    = (float*)alloc((size_t)N_NODES * HID * 4);
    float*  as1   = (float*)alloc((size_t)N_NODES * HEADS * 4);
    float*  ad1   = (float*)alloc((size_t)N_NODES * HEADS * 4);
    float*  as2   = (float*)alloc((size_t)N_NODES * 4);
    float*  ad2   = (float*)alloc((size_t)N_NODES * 4);
    int*    csrp  = (int*)alloc((size_t)N_NODES * CAP * 4);

    const int* srcI = ei;
    const int* dstI = ei + N_EDGES;

    (void)hipMemsetAsync(counts, 0, (size_t)N_NODES * 4, stream);

    // fused: padded-CSR fill + bf16 casts/transposes (1 kernel)
    prep_fill<<<(PREP_ITEMS + 255) / 256, 256, 0, stream>>>(
        srcI, dstI, counts, csrp, x, W1, W2, xb, W1T, W2T);

    // Layer 1: h1(fp8) = xb @ W1; as1/ad1 fused (blockIdx.x = head)
    dim3 g1(F1 / 64, (N_NODES + 127) / 128);
    gemm_att<128, 64, 64, HEADS><<<g1, 256, 0, stream>>>(
        xb, W1T, h1, N_NODES, F1, IN_DIM, at_s1, at_d1, as1, ad1, (ushort*)nullptr);
    gat_agg1<<<(N_NODES + 3) / 4, 256, 0, stream>>>(h1, as1, ad1, counts, csrp, b1, z1);

    // Layer 2: h2(fp8) = z1 @ W2 with fused as2/ad2 epilogue
    dim3 g2(1, (N_NODES + 63) / 64);
    gemm_att<64, 64, 64, 1><<<g2, 256, 0, stream>>>(
        z1, W2T, h2, N_NODES, HID, F1, at_s2, at_d2, as2, ad2, (ushort*)nullptr);
    gat_agg2<<<(N_NODES + 3) / 4, 256, 0, stream>>>(h2, as2, ad2, counts, csrp, b2, z2);

    // fused mean-pool + FC (one block per graph)
    pool_fc<<<N_GRAPHS, 256, 0, stream>>>(z2, batch, fcw, fcb, out);
}

// Round 8
// 285.412 us; speedup vs baseline: 1.3559x; 1.1516x over previous
//
#include <hip/hip_runtime.h>
#include <hip/hip_bf16.h>
#include <cstdint>
#include <cstddef>

// Problem constants (fixed by the reference)
#define N_NODES   50000
#define N_EDGES   640000
#define ETOT      (N_EDGES + N_NODES)   // edges + self loops = 690000
#define IN_DIM    128
#define HID       64
#define HEADS     8
#define F1        (HEADS * HID)         // 512
#define OUT_DIM   2
#define N_GRAPHS  64
#define NEG_SLOPE 0.2f
#define CAP       64   // in-degree ~ Poisson(12.8)+1 self-loop; P(deg>63)~1e-24

typedef __attribute__((ext_vector_type(8))) short s8v;    // 8 x bf16 (4 VGPR)
typedef __attribute__((ext_vector_type(4))) float f32x4;  // MFMA accumulator
typedef __attribute__((ext_vector_type(2))) float f32x2;  // packed f32 pair
typedef unsigned char uchar;
typedef unsigned int  uint;

__device__ __forceinline__ float leakyf(float x) { return x > 0.f ? x : NEG_SLOPE * x; }
__device__ __forceinline__ float eluf(float x)   { return x > 0.f ? x : __expf(x) - 1.f; }

__device__ __forceinline__ float bf2f(ushort u) {
    union { uint32_t i; float f; } c; c.i = ((uint32_t)u) << 16; return c.f;
}
__device__ __forceinline__ ushort f2bf(float f) {
    union { float f; uint32_t i; } c; c.f = f;
    uint32_t r = c.i + 0x7FFFu + ((c.i >> 16) & 1u);   // round-to-nearest-even
    return (ushort)(r >> 16);
}
// HW fp8 e4m3 (OCP on gfx950); sel/word args must be immediates -> templates
template<int SEL>
__device__ __forceinline__ float fp8f(uint w) {
    return __builtin_amdgcn_cvt_f32_fp8(w, SEL);
}
template<bool HI>
__device__ __forceinline__ f32x2 pk8(uint w) {
    return __builtin_amdgcn_cvt_pk_f32_fp8(w, HI);   // 2 fp8 -> 2 f32, 1 instr
}
__device__ __forceinline__ uchar f2fp8(float f) {
    uint p = __builtin_amdgcn_cvt_pk_fp8_f32(f, f, 0u, false);
    return (uchar)(p & 0xFFu);
}

// ----------------------------------- fused prep: padded-CSR fill + casts
#define XW_ITEMS  (N_NODES * IN_DIM / 4)        // 1600000 float4-casts
#define W1_ITEMS  (F1 * IN_DIM)                 // 65536
#define W2_ITEMS  (HID * F1)                    // 32768
#define PREP_ITEMS (ETOT + XW_ITEMS + W1_ITEMS + W2_ITEMS)

__global__ __launch_bounds__(256) void prep_fill(const int* __restrict__ srcI,
                                                 const int* __restrict__ dstI,
                                                 int* __restrict__ counts,
                                                 ushort* __restrict__ csrp,
                                                 const float* __restrict__ x,
                                                 const float* __restrict__ W1,
                                                 const float* __restrict__ W2,
                                                 ushort* __restrict__ xb,
                                                 ushort* __restrict__ W1T,
                                                 ushort* __restrict__ W2T) {
    int i = blockIdx.x * 256 + threadIdx.x;
    if (i < ETOT) {
        int s, d;
        if (i < N_EDGES) { s = srcI[i]; d = dstI[i]; }
        else             { s = d = i - N_EDGES; }
        int slot = atomicAdd(&counts[d], 1);
        if (slot < CAP) csrp[d * CAP + slot] = (ushort)s;
    } else if (i < ETOT + XW_ITEMS) {
        int idx = i - ETOT;
        float4 v = *reinterpret_cast<const float4*>(x + (size_t)idx * 4);
        ushort4 u;
        u.x = f2bf(v.x); u.y = f2bf(v.y); u.z = f2bf(v.z); u.w = f2bf(v.w);
        *reinterpret_cast<ushort4*>(xb + (size_t)idx * 4) = u;
    } else if (i < ETOT + XW_ITEMS + W1_ITEMS) {
        int idx = i - ETOT - XW_ITEMS;
        int n = idx >> 7, k = idx & 127;         // W1T[n][k] = W1[k][n]
        W1T[idx] = f2bf(W1[(size_t)k * F1 + n]);
    } else if (i < PREP_ITEMS) {
        int idx = i - ETOT - XW_ITEMS - W1_ITEMS;
        int n = idx >> 9, k = idx & 511;         // W2T[n][k] = W2[k][n]
        W2T[idx] = f2bf(W2[(size_t)k * HID + n]);
    }
}

// ---------------------------------------------------------------- bf16 GEMM
// C[M,N] = A[M,K] @ BT[N,K]^T, bf16 in, f32 acc, fp8 e4m3 out.
// 1D grid + bijective XCD swizzle (m204): each XCD owns contiguous row
// panels with ALL col blocks -> A panel fetched by exactly one XCD L2.
// BN=64 -> col block == head for layer 1; as/ad logits fused in epilogue.
template<int BM, int BN, int BK, int AH>
__global__ __launch_bounds__(256) void gemm_att(const ushort* __restrict__ A,
                                                const ushort* __restrict__ BT,
                                                uchar* __restrict__ C8,
                                                int M, int N, int K,
                                                const float* __restrict__ att_s,
                                                const float* __restrict__ att_d,
                                                float* __restrict__ as_o,
                                                float* __restrict__ ad_o) {
    // bijective XCD swizzle
    int nwg = gridDim.x;
    int q = nwg >> 3, r = nwg & 7;
    int xcd = blockIdx.x & 7, loc = blockIdx.x >> 3;
    int sid = (xcd < r) ? (xcd * (q + 1) + loc)
                        : (r * (q + 1) + (xcd - r) * q + loc);
    int ncb = N / BN;
    int bx = sid % ncb;          // col block (head)
    int by = sid / ncb;          // row panel

    __shared__ ushort As[BM * BK];   // XOR-swizzled
    __shared__ ushort Bs[BN * BK];
    const int t    = threadIdx.x;
    const int row0 = by * BM;
    const int col0 = bx * BN;
    const int lane = t & 63;
    const int wr   = t >> 6;                 // 0..3, wave row band
    constexpr int FR = BM / 64;              // fragments per wave row band

    f32x4 acc[FR][4];
    #pragma unroll
    for (int i = 0; i < FR; ++i)
        #pragma unroll
        for (int j = 0; j < 4; ++j)
            acc[i][j] = (f32x4){0.f, 0.f, 0.f, 0.f};

    constexpr int A_IT = BM * BK / 8 / 256;  // 16B chunks per thread
    constexpr int B_IT = BN * BK / 8 / 256;

    for (int k0 = 0; k0 < K; k0 += BK) {
        #pragma unroll
        for (int i = 0; i < A_IT; ++i) {
            int ch  = t + 256 * i;
            int rr  = ch >> 3;               // BK*2/16 = 8 chunks per row
            int c16 = ch & 7;
            uint4 v = make_uint4(0u, 0u, 0u, 0u);
            int gr = row0 + rr;
            if (gr < M)
                v = *reinterpret_cast<const uint4*>(A + (size_t)gr * K + k0 + c16 * 8);
            int off = (ch * 16) ^ ((rr & 7) << 4);
            *reinterpret_cast<uint4*>(reinterpret_cast<char*>(As) + off) = v;
        }
        #pragma unroll
        for (int i = 0; i < B_IT; ++i) {
            int ch  = t + 256 * i;
            int rr  = ch >> 3;
            int c16 = ch & 7;
            uint4 v = *reinterpret_cast<const uint4*>(BT + (size_t)(col0 + rr) * K + k0 + c16 * 8);
            int off = (ch * 16) ^ ((rr & 7) << 4);
            *reinterpret_cast<uint4*>(reinterpret_cast<char*>(Bs) + off) = v;
        }
        __syncthreads();
        #pragma unroll
        for (int kk = 0; kk < BK; kk += 32) {
            s8v af[FR], bf[4];
            #pragma unroll
            for (int fr = 0; fr < FR; ++fr) {
                int rr  = wr * (FR * 16) + fr * 16 + (lane & 15);
                int off = (rr * (BK * 2) + kk * 2 + (lane >> 4) * 16) ^ ((rr & 7) << 4);
                af[fr] = *reinterpret_cast<const s8v*>(reinterpret_cast<const char*>(As) + off);
            }
            #pragma unroll
            for (int fc = 0; fc < 4; ++fc) {
                int rr  = fc * 16 + (lane & 15);
                int off = (rr * (BK * 2) + kk * 2 + (lane >> 4) * 16) ^ ((rr & 7) << 4);
                bf[fc] = *reinterpret_cast<const s8v*>(reinterpret_cast<const char*>(Bs) + off);
            }
            #pragma unroll
            for (int fr = 0; fr < FR; ++fr)
                #pragma unroll
                for (int fc = 0; fc < 4; ++fc)
                    acc[fr][fc] = __builtin_amdgcn_mfma_f32_16x16x32_bf16(af[fr], bf[fc], acc[fr][fc], 0, 0, 0);
        }
        __syncthreads();
    }

    // att vectors for this head (col block), at this lane's 4 columns
    float avs[4], avd[4];
    const float* asp = att_s + bx * BN;
    const float* adp = att_d + bx * BN;
    #pragma unroll
    for (int fc = 0; fc < 4; ++fc) {
        avs[fc] = asp[fc * 16 + (lane & 15)];
        avd[fc] = adp[fc * 16 + (lane & 15)];
    }

    // epilogue: C/D layout col=lane&15, row=(lane>>4)*4+reg  [m89-verified]
    #pragma unroll
    for (int fr = 0; fr < FR; ++fr) {
        #pragma unroll
        for (int j = 0; j < 4; ++j) {
            int row = row0 + wr * (FR * 16) + fr * 16 + (lane >> 4) * 4 + j;
            if (row < M) {
                float sv = 0.f, dv = 0.f;
                #pragma unroll
                for (int fc = 0; fc < 4; ++fc) {
                    float c = acc[fr][fc][j];
                    int col = col0 + fc * 16 + (lane & 15);
                    C8[(size_t)row * N + col] = f2fp8(c);
                    sv = fmaf(c, avs[fc], sv);
                    dv = fmaf(c, avd[fc], dv);
                }
                #pragma unroll
                for (int off = 1; off < 16; off <<= 1) {
                    sv += __shfl_xor(sv, off);
                    dv += __shfl_xor(dv, off);
                }
                if ((lane & 15) == 0) {
                    as_o[(size_t)row * AH + bx] = sv;
                    ad_o[(size_t)row * AH + bx] = dv;
                }
            }
        }
    }
}

// ------------------------------------------- layer-1 aggregation (8 heads)
// phase 1: lane = edge -> ONE exp instruction covers 64 edges per head
//          (weights in padded LDS [8][65], conflict-free).
// phase 2: lane = channel-group; 4-deep pipelined fp8 gathers (8B/lane),
//          pk fp8->f32 converts + packed f32 FMAs (v_pk_fma_f32).
__global__ __launch_bounds__(256) void gat_agg1(const uchar* __restrict__ h8,
                                                const float* __restrict__ as,
                                                const float* __restrict__ ad,
                                                const int* __restrict__ counts,
                                                const ushort* __restrict__ csrp,
                                                const float* __restrict__ bias,
                                                ushort* __restrict__ z) {
    __shared__ float lds_w[4][HEADS][CAP + 1];
    int tid  = threadIdx.x;
    int wid  = tid >> 6;
    int dst  = (blockIdx.x * 256 + tid) >> 6;
    int lane = tid & 63;
    if (dst >= N_NODES) return;
    int cnt = min(counts[dst], CAP);
    int hd  = lane >> 3;

    // ---- phase 1: per-edge all-head weights
    int myidx = (lane < cnt) ? (int)csrp[(size_t)dst * CAP + lane] : 0;
    float4 a0 = *reinterpret_cast<const float4*>(as + (size_t)myidx * HEADS);
    float4 a1 = *reinterpret_cast<const float4*>(as + (size_t)myidx * HEADS + 4);
    float4 d0 = *reinterpret_cast<const float4*>(ad + (size_t)dst * HEADS);
    float4 d1 = *reinterpret_cast<const float4*>(ad + (size_t)dst * HEADS + 4);
    lds_w[wid][0][lane] = __expf(leakyf(a0.x + d0.x));
    lds_w[wid][1][lane] = __expf(leakyf(a0.y + d0.y));
    lds_w[wid][2][lane] = __expf(leakyf(a0.z + d0.z));
    lds_w[wid][3][lane] = __expf(leakyf(a0.w + d0.w));
    lds_w[wid][4][lane] = __expf(leakyf(a1.x + d1.x));
    lds_w[wid][5][lane] = __expf(leakyf(a1.y + d1.y));
    lds_w[wid][6][lane] = __expf(leakyf(a1.z + d1.z));
    lds_w[wid][7][lane] = __expf(leakyf(a1.w + d1.w));
    // same wave produces & consumes -> lgkmcnt ordering, no barrier needed

    // ---- phase 2: weighted fp8 gather-accumulate (packed f32 math)
    f32x2 acc2[4];
    acc2[0] = (f32x2){0.f, 0.f}; acc2[1] = (f32x2){0.f, 0.f};
    acc2[2] = (f32x2){0.f, 0.f}; acc2[3] = (f32x2){0.f, 0.f};
    float den = 0.f;
    const uchar* hb = h8 + (size_t)lane * 8;     // this lane's 8 channels
    for (int j0 = 0; j0 < cnt; j0 += 4) {
        int n = cnt - j0;                         // wave-uniform
        int s0 = 0, s1 = 0, s2 = 0, s3 = 0;
        uint2 v0 = {}, v1 = {}, v2 = {}, v3 = {};
        float w0 = 0.f, w1 = 0.f, w2 = 0.f, w3 = 0.f;
        s0 = __shfl(myidx, j0);
        v0 = *reinterpret_cast<const uint2*>(hb + (size_t)s0 * F1);
        w0 = lds_w[wid][hd][j0];
        if (n > 1) {
            s1 = __shfl(myidx, j0 + 1);
            v1 = *reinterpret_cast<const uint2*>(hb + (size_t)s1 * F1);
            w1 = lds_w[wid][hd][j0 + 1];
        }
        if (n > 2) {
            s2 = __shfl(myidx, j0 + 2);
            v2 = *reinterpret_cast<const uint2*>(hb + (size_t)s2 * F1);
            w2 = lds_w[wid][hd][j0 + 2];
        }
        if (n > 3) {
            s3 = __shfl(myidx, j0 + 3);
            v3 = *reinterpret_cast<const uint2*>(hb + (size_t)s3 * F1);
            w3 = lds_w[wid][hd][j0 + 3];
        }
        {
            f32x2 wv = (f32x2){w0, w0};
            den += w0;
            acc2[0] += pk8<false>(v0.x) * wv;
            acc2[1] += pk8<true >(v0.x) * wv;
            acc2[2] += pk8<false>(v0.y) * wv;
            acc2[3] += pk8<true >(v0.y) * wv;
        }
        if (n > 1) {
            f32x2 wv = (f32x2){w1, w1};
            den += w1;
            acc2[0] += pk8<false>(v1.x) * wv;
            acc2[1] += pk8<true >(v1.x) * wv;
            acc2[2] += pk8<false>(v1.y) * wv;
            acc2[3] += pk8<true >(v1.y) * wv;
        }
        if (n > 2) {
            f32x2 wv = (f32x2){w2, w2};
            den += w2;
            acc2[0] += pk8<false>(v2.x) * wv;
            acc2[1] += pk8<true >(v2.x) * wv;
            acc2[2] += pk8<false>(v2.y) * wv;
            acc2[3] += pk8<true >(v2.y) * wv;
        }
        if (n > 3) {
            f32x2 wv = (f32x2){w3, w3};
            den += w3;
            acc2[0] += pk8<false>(v3.x) * wv;
            acc2[1] += pk8<true >(v3.x) * wv;
            acc2[2] += pk8<false>(v3.y) * wv;
            acc2[3] += pk8<true >(v3.y) * wv;
        }
    }
    float inv = 1.f / (den + 1e-16f);
    s8v ov;
    #pragma unroll
    for (int c = 0; c < 8; ++c) {
        float v = acc2[c >> 1][c & 1] * inv + bias[lane * 8 + c];
        ov[c] = (short)f2bf(eluf(v));
    }
    *reinterpret_cast<s8v*>(z + (size_t)dst * F1 + lane * 8) = ov;
}

// ------------------------------------------- layer-2 aggregation (1 head)
__global__ __launch_bounds__(256) void gat_agg2(const uchar* __restrict__ h8,
                                                const float* __restrict__ as,
                                                const float* __restrict__ ad,
                                                const int* __restrict__ counts,
                                                const ushort* __restrict__ csrp,
                                                const float* __restrict__ bias,
                                                float* __restrict__ z) {
    int dst  = (blockIdx.x * 256 + threadIdx.x) >> 6;
    int lane = threadIdx.x & 63;
    if (dst >= N_NODES) return;
    int cnt = min(counts[dst], CAP);
    float adv = ad[dst];

    int myidx = (lane < cnt) ? (int)csrp[(size_t)dst * CAP + lane] : 0;
    float wl  = (lane < cnt) ? __expf(leakyf(as[myidx] + adv)) : 0.f;
    float den = wl;
    #pragma unroll
    for (int off = 32; off > 0; off >>= 1) den += __shfl_xor(den, off);

    float acc = 0.f;
    for (int j0 = 0; j0 < cnt; j0 += 4) {
        int n = cnt - j0;
        int s0 = 0, s1 = 0, s2 = 0, s3 = 0;
        float w0 = 0.f, w1 = 0.f, w2 = 0.f, w3 = 0.f;
        uint b0 = 0, b1 = 0, b2 = 0, b3 = 0;
        s0 = __shfl(myidx, j0);     w0 = __shfl(wl, j0);
        b0 = h8[(size_t)s0 * HID + lane];
        if (n > 1) { s1 = __shfl(myidx, j0 + 1); w1 = __shfl(wl, j0 + 1); b1 = h8[(size_t)s1 * HID + lane]; }
        if (n > 2) { s2 = __shfl(myidx, j0 + 2); w2 = __shfl(wl, j0 + 2); b2 = h8[(size_t)s2 * HID + lane]; }
        if (n > 3) { s3 = __shfl(myidx, j0 + 3); w3 = __shfl(wl, j0 + 3); b3 = h8[(size_t)s3 * HID + lane]; }
        acc = fmaf(w0, fp8f<0>(b0), acc);
        if (n > 1) acc = fmaf(w1, fp8f<0>(b1), acc);
        if (n > 2) acc = fmaf(w2, fp8f<0>(b2), acc);
        if (n > 3) acc = fmaf(w3, fp8f<0>(b3), acc);
    }
    float v = acc / (den + 1e-16f) + bias[lane];
    z[(size_t)dst * HID + lane] = eluf(v);
}

// --------------------------------------- fused mean-pool + FC (per graph)
// 8 waves + 4 independent accumulators per wave (old version was MLP=1).
__global__ __launch_bounds__(512) void pool_fc(const float* __restrict__ z,
                                               const int* __restrict__ batch,
                                               const float* __restrict__ fc_w,
                                               const float* __restrict__ fc_b,
                                               float* __restrict__ out) {
    int g = blockIdx.x;
    int t = threadIdx.x, lane = t & 63, w = t >> 6;   // 8 waves
    auto lb = [&](int key) {
        int lo = 0, hi = N_NODES;
        while (lo < hi) { int mid = (lo + hi) >> 1; if (batch[mid] < key) lo = mid + 1; else hi = mid; }
        return lo;
    };
    int lo = lb(g), hi = lb(g + 1);
    float a0 = 0.f, a1 = 0.f, a2 = 0.f, a3 = 0.f;
    for (int n0 = lo + (w << 2); n0 < hi; n0 += 32) {
        a0 += z[(size_t)n0 * HID + lane];
        if (n0 + 1 < hi) a1 += z[(size_t)(n0 + 1) * HID + lane];
        if (n0 + 2 < hi) a2 += z[(size_t)(n0 + 2) * HID + lane];
        if (n0 + 3 < hi) a3 += z[(size_t)(n0 + 3) * HID + lane];
    }
    float acc = (a0 + a1) + (a2 + a3);
    __shared__ float sh[8][HID];
    sh[w][lane] = acc;
    __syncthreads();
    if (w == 0) {
        float s = 0.f;
        #pragma unroll
        for (int i = 0; i < 8; ++i) s += sh[i][lane];
        float cntf = fmaxf((float)(hi - lo), 1.f);
        float mean = s / cntf;
        float p0 = mean * fc_w[lane * OUT_DIM + 0];
        float p1 = mean * fc_w[lane * OUT_DIM + 1];
        #pragma unroll
        for (int off = 32; off > 0; off >>= 1) {
            p0 += __shfl_xor(p0, off);
            p1 += __shfl_xor(p1, off);
        }
        if (lane == 0) {
            out[g * OUT_DIM + 0] = p0 + fc_b[0];
            out[g * OUT_DIM + 1] = p1 + fc_b[1];
        }
    }
}

// ---------------------------------------------------------------- launcher
extern "C" void kernel_launch(void* const* d_in, const int* in_sizes, int n_in,
                              void* d_out, int out_size, void* d_ws, size_t ws_size,
                              hipStream_t stream) {
    const float* x    = (const float*)d_in[0];
    const float* W1   = (const float*)d_in[1];
    const float* at_s1= (const float*)d_in[2];
    const float* at_d1= (const float*)d_in[3];
    const float* b1   = (const float*)d_in[4];
    const float* W2   = (const float*)d_in[5];
    const float* at_s2= (const float*)d_in[6];
    const float* at_d2= (const float*)d_in[7];
    const float* b2   = (const float*)d_in[8];
    const float* fcw  = (const float*)d_in[9];
    const float* fcb  = (const float*)d_in[10];
    const int*   ei   = (const int*)d_in[11];
    const int*   batch= (const int*)d_in[12];
    float* out = (float*)d_out;

    char* p = (char*)d_ws;
    auto alloc = [&](size_t bytes) {
        char* r = p;
        p += (bytes + 255) & ~size_t(255);
        return r;
    };
    int*    counts= (int*)alloc((size_t)N_NODES * 4);
    ushort* xb    = (ushort*)alloc((size_t)N_NODES * IN_DIM * 2);
    ushort* W1T   = (ushort*)alloc((size_t)F1 * IN_DIM * 2);
    ushort* W2T   = (ushort*)alloc((size_t)HID * F1 * 2);
    uchar*  h1    = (uchar*)alloc((size_t)N_NODES * F1);       // fp8 e4m3
    ushort* z1    = (ushort*)alloc((size_t)N_NODES * F1 * 2);  // bf16
    uchar*  h2    = (uchar*)alloc((size_t)N_NODES * HID);      // fp8 e4m3
    float*  z2    = (float*)alloc((size_t)N_NODES * HID * 4);
    float*  as1   = (float*)alloc((size_t)N_NODES * HEADS * 4);
    float*  ad1   = (float*)alloc((size_t)N_NODES * HEADS * 4);
    float*  as2   = (float*)alloc((size_t)N_NODES * 4);
    float*  ad2   = (float*)alloc((size_t)N_NODES * 4);
    ushort* csrp  = (ushort*)alloc((size_t)N_NODES * CAP * 2);

    const int* srcI = ei;
    const int* dstI = ei + N_EDGES;

    (void)hipMemsetAsync(counts, 0, (size_t)N_NODES * 4, stream);

    // fused: padded-CSR fill + bf16 casts/transposes (1 kernel)
    prep_fill<<<(PREP_ITEMS + 255) / 256, 256, 0, stream>>>(
        srcI, dstI, counts, csrp, x, W1, W2, xb, W1T, W2T);

    // Layer 1: h1(fp8) = xb @ W1; as1/ad1 fused; 1D grid + XCD swizzle
    int nwg1 = (F1 / 64) * ((N_NODES + 127) / 128);   // 8 * 391 = 3128
    gemm_att<128, 64, 64, HEADS><<<nwg1, 256, 0, stream>>>(
        xb, W1T, h1, N_NODES, F1, IN_DIM, at_s1, at_d1, as1, ad1);
    gat_agg1<<<(N_NODES + 3) / 4, 256, 0, stream>>>(h1, as1, ad1, counts, csrp, b1, z1);

    // Layer 2: h2(fp8) = z1 @ W2 with fused as2/ad2 epilogue
    int nwg2 = 1 * ((N_NODES + 63) / 64);             // 782
    gemm_att<64, 64, 64, 1><<<nwg2, 256, 0, stream>>>(
        z1, W2T, h2, N_NODES, HID, F1, at_s2, at_d2, as2, ad2);
    gat_agg2<<<(N_NODES + 3) / 4, 256, 0, stream>>>(h2, as2, ad2, counts, csrp, b2, z2);

    // fused mean-pool + FC (one block per graph)
    pool_fc<<<N_GRAPHS, 512, 0, stream>>>(z2, batch, fcw, fcb, out);
}